// Round 11
// baseline (7650.417 us; speedup 1.0000x reference)
//
#include <hip/hip_runtime.h>
#include <hip/hip_bf16.h>
#include <cstddef>

#define kT 256
#define kB 128
#define kINP 512
#define kH 512
#define kK 32
#define kR 64
#define kNEG (-1e30f)

// ---------------------------------------------------------------------------
// agent-scope (device-coherent, L1/L2-bypassing) accessors, RELAXED order.
// Ordering between the pair blocks: set_flag's __syncthreads drains vmcnt(0)
// per wave before tid0 stores the flag; the partner tid0-spins the flag,
// barriers, then ag_loads the data. Protocol validated r3-r5/r9/r10.
// ---------------------------------------------------------------------------
__device__ __forceinline__ void ag_store(float* p, float v) {
    __hip_atomic_store(p, v, __ATOMIC_RELAXED, __HIP_MEMORY_SCOPE_AGENT);
}
__device__ __forceinline__ float ag_load(const float* p) {
    return __hip_atomic_load(p, __ATOMIC_RELAXED, __HIP_MEMORY_SCOPE_AGENT);
}

// fast tanh for attention scores (error ~1e-7, stable at +-inf)
__device__ __forceinline__ float ftanh(float x)
{
    float e = __expf(2.0f * x);
    return 1.0f - 2.0f * __builtin_amdgcn_rcpf(e + 1.0f);
}

// ---------------------------------------------------------------------------
// XU = x @ Uw + Ub.  64x64 tile, BK=32, 256 threads, 4x4 acc/thread.
// ---------------------------------------------------------------------------
__global__ __launch_bounds__(256) void gemm_xu(
    const float* __restrict__ A, const float* __restrict__ W,
    const float* __restrict__ bias, float* __restrict__ C)
{
    __shared__ float At[32][68];   // A tile transposed: At[k][m]
    __shared__ float Ws[32][68];
    const int tid = threadIdx.x;
    const int n0 = blockIdx.x * 64;
    const int m0 = blockIdx.y * 64;
    const int tx = tid & 15, ty = tid >> 4;
    const int arow = tid >> 3, ak = (tid & 7) << 2;
    const int wrow = tid >> 4, wc = (tid & 15) << 2;

    float acc[4][4] = {};

    for (int k0 = 0; k0 < kINP; k0 += 32) {
        float4 a0 = *reinterpret_cast<const float4*>(&A[(size_t)(m0 + arow) * kINP + k0 + ak]);
        float4 a1 = *reinterpret_cast<const float4*>(&A[(size_t)(m0 + 32 + arow) * kINP + k0 + ak]);
        float4 w0 = *reinterpret_cast<const float4*>(&W[(size_t)(k0 + wrow) * kH + n0 + wc]);
        float4 w1 = *reinterpret_cast<const float4*>(&W[(size_t)(k0 + wrow + 16) * kH + n0 + wc]);
        __syncthreads();
        At[ak + 0][arow] = a0.x; At[ak + 1][arow] = a0.y;
        At[ak + 2][arow] = a0.z; At[ak + 3][arow] = a0.w;
        At[ak + 0][32 + arow] = a1.x; At[ak + 1][32 + arow] = a1.y;
        At[ak + 2][32 + arow] = a1.z; At[ak + 3][32 + arow] = a1.w;
        *reinterpret_cast<float4*>(&Ws[wrow][wc]) = w0;
        *reinterpret_cast<float4*>(&Ws[wrow + 16][wc]) = w1;
        __syncthreads();
#pragma unroll
        for (int kk = 0; kk < 32; ++kk) {
            float4 a4 = *reinterpret_cast<float4*>(&At[kk][ty * 4]);
            float4 w4 = *reinterpret_cast<float4*>(&Ws[kk][tx * 4]);
            float a_[4] = {a4.x, a4.y, a4.z, a4.w};
            float w_[4] = {w4.x, w4.y, w4.z, w4.w};
#pragma unroll
            for (int r = 0; r < 4; ++r)
#pragma unroll
                for (int c = 0; c < 4; ++c)
                    acc[r][c] += a_[r] * w_[c];
        }
    }

#pragma unroll
    for (int r = 0; r < 4; ++r) {
        int m = m0 + ty * 4 + r;
#pragma unroll
        for (int c = 0; c < 4; ++c) {
            int n = n0 + tx * 4 + c;
            C[(size_t)m * kH + n] = acc[r][c] + bias[n];
        }
    }
}

__global__ __launch_bounds__(256) void init_flags_k(int* __restrict__ flags)
{
    int i = blockIdx.x * 256 + threadIdx.x;
    if (i < kB * 3 * 2) flags[i] = 0;
}

// ---------------------------------------------------------------------------
// Pair-split persistent recurrence — r10 structure with ONE change: matvec-B
// pass 2 (va' = st @ Vaw) is folded into the A-phase as a wave split.
// Waves 8-15 compute va partials (full k, from st_{t-1} still in st_sh)
// PRE-WAIT, overlapping the fC spin; waves 0-7 compute u partials (own-k
// pre-wait, partner-k post-wait). One barrier + one 512-thread dual reduce
// replaces pass 2's separate loop + 2 barriers + reduce.
// ---------------------------------------------------------------------------
__global__ __launch_bounds__(1024) void rnn_pair(
    const float* __restrict__ Vw, const float* __restrict__ Vaw,
    const float* __restrict__ Uaw, const float* __restrict__ vvec,
    const float* __restrict__ XU, float* __restrict__ lngU,
    float* __restrict__ hs, float* __restrict__ esx,
    float* __restrict__ stx, int* __restrict__ flags)
{
    extern __shared__ float dyn[];
    float* shortH = dyn;               // [32][256]
    float* shortU = dyn + 32 * 256;    // [32][256]
    float* longH  = dyn + 64 * 256;    // [64][256]
    float* part   = dyn + 128 * 256;   // [16][264]
    const int PSTR = 264;

    const int bid = blockIdx.x;
    const int b = bid >> 1, half = bid & 1;
    const int C0 = half << 8;            // own column base
    const int P0 = (half ^ 1) << 8;      // partner column base
    const int tid = threadIdx.x;
    const int kq = tid >> 6;             // 0..15 (wave id / k-split group)
    const int kq8 = kq & 7;              // k-split id within the 8-wave group
    const int lane = tid & 63;
    const int c4 = lane << 2;            // float4 col offset within half

    __shared__ __align__(16) float h_sh[512];     // full h_{t-1}
    __shared__ __align__(16) float st_sh[512];    // full st
    __shared__ __align__(16) float va_sh[256];    // own cols of va
    __shared__ __align__(16) float v_sh[256];     // own cols of v
    __shared__ float es_own[96], es_sh[96], w_sh[96];
    __shared__ int   rowm[96];
    __shared__ float lsc_sh[kT];
    __shared__ float buck_sh[kR];
    __shared__ int   lidx_sh[kR];
    __shared__ int   fcnt_sh, evict_pos;
    __shared__ float red0, red1;

    float* lngU_b = lngU + (size_t)bid * kR * 256;

    int* fC_own = &flags[(b * 3 + 0) * 2 + half];
    int* fB_own = &flags[(b * 3 + 1) * 2 + half];
    int* fS_own = &flags[(b * 3 + 2) * 2 + half];
    int* fC_par = &flags[(b * 3 + 0) * 2 + (half ^ 1)];
    int* fB_par = &flags[(b * 3 + 1) * 2 + (half ^ 1)];
    int* fS_par = &flags[(b * 3 + 2) * 2 + (half ^ 1)];

    auto wait_ge = [&](int* f, int target) {
        if (tid == 0) {
            while (__hip_atomic_load(f, __ATOMIC_RELAXED, __HIP_MEMORY_SCOPE_AGENT) < target)
                __builtin_amdgcn_s_sleep(1);
        }
        __syncthreads();
    };
    auto set_flag = [&](int* f, int val) {
        __syncthreads();   // drains vmcnt(0): prior agent stores at coherence point
        if (tid == 0)
            __hip_atomic_store(f, val, __ATOMIC_RELAXED, __HIP_MEMORY_SCOPE_AGENT);
    };

    // ---- prologue (t = 0): st_0 = pre = XU[0][b]; h_0 = tanh(pre)
    if (tid < 256) { v_sh[tid] = vvec[C0 + tid]; lsc_sh[tid] = 0.0f; }
    if (tid < kR) { buck_sh[tid] = 0.0f; lidx_sh[tid] = -1; }
    if (tid == 0) fcnt_sh = 0;
    if (tid < 512) st_sh[tid] = XU[(size_t)b * kH + tid];   // st_0 = pre
    __syncthreads();
    if (tid < 256) {
        float h0 = tanhf(st_sh[C0 + tid]);
        h_sh[C0 + tid] = h0;
        shortH[tid] = h0;                       // slot 0 <- h_0
        ag_store(&hs[(size_t)b * kH + C0 + tid], h0);
    }
    set_flag(fC_own, 1);
    // (va_0 is computed in-loop at t=1 by the fused A-phase from st_sh)

    for (int t = 1; t < kT; ++t) {
        // XU[t] prefetch for the matvec-B epilogue
        float xu_reg = 0.0f;
        if (tid < 256) xu_reg = XU[((size_t)t * kB + b) * kH + C0 + tid];

        // ---- fused A-phase (pre-wait):
        //      waves 8-15: va partials = st_{t-1} @ Vaw[:, C], full k
        //      waves 0-7:  u partials = h_{t-1} @ Uaw[:, C], own-k half
        float4 accA = {0, 0, 0, 0};
        if (kq >= 8) {
#pragma unroll 8
            for (int k = kq8; k < kH; k += 8) {
                float s = st_sh[k];
                const float4 w = *reinterpret_cast<const float4*>(&Vaw[(size_t)k * kH + C0 + c4]);
                accA.x += s * w.x; accA.y += s * w.y; accA.z += s * w.z; accA.w += s * w.w;
            }
        } else {
#pragma unroll 8
            for (int k = C0 + kq8; k < C0 + 256; k += 8) {
                float s = h_sh[k];
                const float4 w = *reinterpret_cast<const float4*>(&Uaw[(size_t)k * kH + C0 + c4]);
                accA.x += s * w.x; accA.y += s * w.y; accA.z += s * w.z; accA.w += s * w.w;
            }
        }
        if (tid < 96) {
            int row;
            if (tid < kK) { int md = (t + 31 - tid) & 31; row = t - 1 - md; }
            else row = lidx_sh[tid - kK];     // >=0 means slot filled
            rowm[tid] = row;
        }
        wait_ge(fC_par, t);
        if (tid < 256) h_sh[P0 + tid] = ag_load(&hs[((size_t)(t - 1) * kB + b) * kH + P0 + tid]);
        __syncthreads();                                              // B1
        // ---- A-phase (post-wait): waves 0-7, u partner-k half
        if (kq < 8) {
#pragma unroll 8
            for (int k = P0 + kq8; k < P0 + 256; k += 8) {
                float s = h_sh[k];
                const float4 w = *reinterpret_cast<const float4*>(&Uaw[(size_t)k * kH + C0 + c4]);
                accA.x += s * w.x; accA.y += s * w.y; accA.z += s * w.z; accA.w += s * w.w;
            }
        }
        *reinterpret_cast<float4*>(&part[kq * PSTR + c4]) = accA;
        __syncthreads();                                              // B2
        if (tid < 512) {   // dual reduce: u from rows 0-7, va from rows 8-15
            int col = tid & 255;
            float acc = 0.0f;
            if (tid < 256) {
#pragma unroll
                for (int j = 0; j < 8; ++j) acc += part[j * PSTR + col];
                shortU[((t - 1) & 31) * 256 + col] = acc;   // slot (t-1)%32
            } else {
#pragma unroll
                for (int j = 8; j < 16; ++j) acc += part[j * PSTR + col];
                va_sh[col] = acc;
            }
        }
        __syncthreads();                                              // B3

        // ---- es partials over own cols: wave kq handles rows m = kq + 16r
        {
            float4 uu[6];
            int rv[6];
#pragma unroll
            for (int r = 0; r < 6; ++r) {
                int m = kq + (r << 4);
                int row = rowm[m];
                rv[r] = row;
                uu[r] = make_float4(0.f, 0.f, 0.f, 0.f);
                if (row >= 0) {
                    const float* up = (m < kK) ? &shortU[m * 256]
                                               : &lngU_b[(size_t)(m - kK) * 256];
                    uu[r] = *reinterpret_cast<const float4*>(&up[c4]);
                }
            }
            const float4 vav = *reinterpret_cast<const float4*>(&va_sh[c4]);
            const float4 vvv = *reinterpret_cast<const float4*>(&v_sh[c4]);
#pragma unroll
            for (int r = 0; r < 6; ++r) {
                float p = 0.0f;
                if (rv[r] >= 0) {
                    p = vvv.x * ftanh(vav.x + uu[r].x) + vvv.y * ftanh(vav.y + uu[r].y)
                      + vvv.z * ftanh(vav.z + uu[r].z) + vvv.w * ftanh(vav.w + uu[r].w);
                }
#pragma unroll
                for (int off = 32; off; off >>= 1) p += __shfl_down(p, off);
                if (lane == 0) es_own[kq + (r << 4)] = p;
            }
        }
        __syncthreads();
        if (tid < 96) ag_store(&esx[((size_t)b * 2 + half) * 96 + tid], es_own[tid]);
        set_flag(fB_own, t);
        wait_ge(fB_par, t);
        if (tid < 96) {
            float e = kNEG;
            if (rowm[tid] >= 0)
                e = es_own[tid] + ag_load(&esx[((size_t)b * 2 + (half ^ 1)) * 96 + tid]);
            es_sh[tid] = e;
        }
        __syncthreads();

        // ---- softmax over 96 (redundant in both halves, bitwise identical)
        if (tid < 64) {
            float a = es_sh[tid];
            float c = (tid < 32) ? es_sh[64 + tid] : kNEG;
            float mx = fmaxf(a, c);
#pragma unroll
            for (int off = 32; off; off >>= 1) mx = fmaxf(mx, __shfl_xor(mx, off));
            if (tid == 0) red0 = mx;
        }
        __syncthreads();
        if (tid < 96) w_sh[tid] = __expf(es_sh[tid] - red0);
        __syncthreads();
        if (tid < 64) {
            float a = w_sh[tid] + ((tid < 32) ? w_sh[64 + tid] : 0.0f);
#pragma unroll
            for (int off = 32; off; off >>= 1) a += __shfl_xor(a, off);
            if (tid == 0) red1 = 1.0f / a;
        }
        __syncthreads();

        // ---- ct partials over own cols (shortH / longH, both LDS)
        {
            float4 hv[6]; float wq[6];
#pragma unroll
            for (int r = 0; r < 6; ++r) {
                int m = kq + (r << 4);
                int row = rowm[m];
                hv[r] = make_float4(0.f, 0.f, 0.f, 0.f); wq[r] = 0.0f;
                if (row >= 0) {
                    const float* hp = (m < kK) ? &shortH[m * 256]
                                               : &longH[(m - kK) * 256];
                    hv[r] = *reinterpret_cast<const float4*>(&hp[c4]);
                    wq[r] = w_sh[m];
                }
            }
            float4 acc = {0, 0, 0, 0};
#pragma unroll
            for (int r = 0; r < 6; ++r) {
                acc.x += wq[r] * hv[r].x; acc.y += wq[r] * hv[r].y;
                acc.z += wq[r] * hv[r].z; acc.w += wq[r] * hv[r].w;
            }
            *reinterpret_cast<float4*>(&part[kq * PSTR + c4]) = acc;
        }
        __syncthreads();
        if (tid < 256) {
            float ct = 0.0f;
#pragma unroll
            for (int j = 0; j < 16; ++j) ct += part[j * PSTR + tid];
            float stv = 0.5f * (h_sh[C0 + tid] + ct * red1);
            st_sh[C0 + tid] = stv;
            ag_store(&stx[(size_t)b * kH + C0 + tid], stv);
        }
        set_flag(fS_own, t);

        // ---- long_scores accumulation, then eviction decision (ref order)
        if (tid < kK) {
            int row = rowm[tid];
            if (row >= 0) lsc_sh[row] += w_sh[tid] * red1;
        }
        __syncthreads();
        if (tid == 0) {
            int ep = -1;
            if (t >= kK) {
                float score = lsc_sh[t - kK];
                int fc = fcnt_sh;
                bool nf = fc < kR;
                float mn = buck_sh[0]; int mp = 0;
                for (int r = 1; r < kR; ++r) {
                    float bv = buck_sh[r];
                    if (bv < mn) { mn = bv; mp = r; }
                }
                if (nf || score > mn) {
                    ep = nf ? fc : mp;
                    lidx_sh[ep] = t - kK;
                    buck_sh[ep] = score;
                    if (nf) fcnt_sh = fc + 1;
                }
            }
            evict_pos = ep;
        }
        __syncthreads();
        // evicted candidate = h_{t-32} / u_{t-32} in slot t%32 (copy before
        // the slot is overwritten with h_t below)
        if (evict_pos >= 0 && tid < 256) {
            longH[evict_pos * 256 + tid] = shortH[(t & 31) * 256 + tid];
            lngU_b[(size_t)evict_pos * 256 + tid] = shortU[(t & 31) * 256 + tid];
        }

        // ---- matvec B pass 1 (Vw): h_pre[C] = st @ Vw[:, C] + XU[t]
        {
            float4 aw = {0, 0, 0, 0};
#pragma unroll 8
            for (int k = C0 + kq; k < C0 + 256; k += 16) {
                float s = st_sh[k];
                const float4 w = *reinterpret_cast<const float4*>(&Vw[(size_t)k * kH + C0 + c4]);
                aw.x += s * w.x; aw.y += s * w.y; aw.z += s * w.z; aw.w += s * w.w;
            }
            wait_ge(fS_par, t);
            if (tid < 256) st_sh[P0 + tid] = ag_load(&stx[(size_t)b * kH + P0 + tid]);
            __syncthreads();
#pragma unroll 8
            for (int k = P0 + kq; k < P0 + 256; k += 16) {
                float s = st_sh[k];
                const float4 w = *reinterpret_cast<const float4*>(&Vw[(size_t)k * kH + C0 + c4]);
                aw.x += s * w.x; aw.y += s * w.y; aw.z += s * w.z; aw.w += s * w.w;
            }
            *reinterpret_cast<float4*>(&part[kq * PSTR + c4]) = aw;
        }
        __syncthreads();
        if (tid < 256) {
            float hpre = xu_reg;
#pragma unroll
            for (int j = 0; j < 16; ++j) hpre += part[j * PSTR + tid];
            float hv = tanhf(hpre);
            h_sh[C0 + tid] = hv;
            shortH[(t & 31) * 256 + tid] = hv;      // slot t%32 <- h_t
            ag_store(&hs[((size_t)t * kB + b) * kH + C0 + tid], hv);
        }
        set_flag(fC_own, t + 1);   // loop-end barrier + unblock partner
    }
}

// ---------------------------------------------------------------------------
extern "C" void kernel_launch(void* const* d_in, const int* in_sizes, int n_in,
                              void* d_out, int out_size, void* d_ws, size_t ws_size,
                              hipStream_t stream)
{
    const float* x   = (const float*)d_in[0];
    const float* Uw  = (const float*)d_in[1];
    const float* Ub  = (const float*)d_in[2];
    const float* Vw  = (const float*)d_in[3];
    const float* Uaw = (const float*)d_in[4];
    const float* Vaw = (const float*)d_in[5];
    const float* vv  = (const float*)d_in[6];
    float* hs = (float*)d_out;

    float* ws = (float*)d_ws;
    const size_t TBH = (size_t)kT * kB * kH;
    float* XU   = ws;                            // T*B*H
    float* lngU = XU + TBH;                      // 2*B * 64 * 256
    float* esx  = lngU + (size_t)2 * kB * kR * 256;
    float* stx  = esx + (size_t)kB * 2 * 96;     // B*H
    int*   flags = (int*)(stx + (size_t)kB * kH);  // B*3*2

    // dynamic LDS: shortH(32K) + shortU(32K) + longH(64K) + part(16.5K)
    const int dyn_bytes = (32 * 256 + 32 * 256 + 64 * 256 + 16 * 264) * 4;
    hipFuncSetAttribute(reinterpret_cast<const void*>(rnn_pair),
                        hipFuncAttributeMaxDynamicSharedMemorySize, dyn_bytes);

    init_flags_k<<<3, 256, 0, stream>>>(flags);

    // XU = x @ Uw + Ub
    gemm_xu<<<dim3(kH / 64, (kT * kB) / 64), 256, 0, stream>>>(x, Uw, Ub, XU);

    // pair-split recurrence: 2 blocks per batch element, 1024 threads each
    rnn_pair<<<2 * kB, 1024, dyn_bytes, stream>>>(
        Vw, Vaw, Uaw, vv, XU, lngU, hs, esx, stx, flags);
}